// Round 5
// baseline (466.384 us; speedup 1.0000x reference)
//
#include <hip/hip_runtime.h>
#include <hip/hip_bf16.h>

// SplitMLP: B=128, C=16, V=32, H=64, O=4, G=10000
// v6 = v3 (best: 120us, barrier-free wave-per-group) + two levers:
//  (1) items loads are NONTEMPORAL (nt): 164MB stream stops thrashing the
//      256MB Infinity Cache, so the 136MB of weights become ~L3-resident and
//      the two memory paths (HBM stream for items, L3 hits for weights) run
//      in parallel instead of serializing at the ~2.6 TB/s L3-hit path that
//      pinned all five prior structures.
//  (2) __launch_bounds__(256,8): prior versions self-capped at 4 waves/EU
//      (39% measured occupancy). VGPR=60 and LDS=15KB both fit 8 blocks/CU.
// Everything else is byte-identical to v3: one wave = one group, 8 N-tiles of
// 16 batches, rolling items prefetch, zero in-loop barriers, wave-private Hb.
// Numerics identical (same frag math, K-order, f32 bias adds).

typedef __bf16 v8bf __attribute__((ext_vector_type(8)));
typedef __bf16 v4bf __attribute__((ext_vector_type(4)));
typedef float  v4f  __attribute__((ext_vector_type(4)));

#define B_   128
#define C_   16
#define V_   32
#define H_   64
#define O_   4
#define G_   10000
#define GPB  4
#define DS_  24   // Dl stride (elems): 48B rows -> 16B-aligned, ~2-way banks (free)
#define HS_  72   // Hb stride (elems): 144B -> 16B-aligned, 2-way banks (free)

__device__ __forceinline__ v4bf cvt4(float4 f) {
  v4bf r;
  r[0] = (__bf16)f.x; r[1] = (__bf16)f.y; r[2] = (__bf16)f.z; r[3] = (__bf16)f.w;
  return r;
}
__device__ __forceinline__ v8bf cvt8(float4 lo, float4 hi) {
  v8bf r;
  r[0] = (__bf16)lo.x; r[1] = (__bf16)lo.y; r[2] = (__bf16)lo.z; r[3] = (__bf16)lo.w;
  r[4] = (__bf16)hi.x; r[5] = (__bf16)hi.y; r[6] = (__bf16)hi.z; r[7] = (__bf16)hi.w;
  return r;
}
__device__ __forceinline__ v8bf cvt8v(v4f lo, v4f hi) {
  v8bf r;
  r[0] = (__bf16)lo[0]; r[1] = (__bf16)lo[1]; r[2] = (__bf16)lo[2]; r[3] = (__bf16)lo[3];
  r[4] = (__bf16)hi[0]; r[5] = (__bf16)hi[1]; r[6] = (__bf16)hi[2]; r[7] = (__bf16)hi[3];
  return r;
}
__device__ __forceinline__ v8bf gload8(const float* __restrict__ p) {
  const float4* p4 = reinterpret_cast<const float4*>(p);
  return cvt8(p4[0], p4[1]);
}

__global__ __launch_bounds__(256, 8)
void splitmlp_kernel(const float* __restrict__ day,
                     const float* __restrict__ items,
                     const float* __restrict__ W1d,
                     const float* __restrict__ W1v,
                     const float* __restrict__ b1,
                     const float* __restrict__ W2,
                     const float* __restrict__ b2,
                     float* __restrict__ out) {
  __shared__ __bf16 Dl[B_ * DS_];       //  6,144 B  day bf16 [b][16 used]
  __shared__ __bf16 Hb[4][16 * HS_];    //  9,216 B  per-wave h [batch16][hidden64]

  const int t    = threadIdx.x;
  const int w    = t >> 6;
  const int lane = t & 63;
  const int c    = lane & 15;
  const int q    = lane >> 4;
  const int g    = blockIdx.x * GPB + w;   // this wave's group

  v8bf zf;
#pragma unroll
  for (int i = 0; i < 8; ++i) zf[i] = (__bf16)0.0f;
  const v4f zero = {0.f, 0.f, 0.f, 0.f};

  // ---- day global loads first (feed the one-time LDS stage) ----
  float4 dd[2];
  {
    const float4* d4 = reinterpret_cast<const float4*>(day);
    dd[0] = d4[t];
    dd[1] = d4[t + 256];
  }

  // ---- task-start load burst: W1, W2, b1, b2, items tile-0 (all in flight) ----
  const float* W1dg = W1d + (size_t)g * (H_ * C_);
  const float* W1vg = W1v + (size_t)g * (H_ * V_);
  float4 s0[4][2], s1[4][2];
#pragma unroll
  for (int m = 0; m < 4; ++m) {
    const int h = m * 16 + c;
    // frag0 k=q*8: q<2 -> W1d[h][q*8..+8); q>=2 -> W1v[h][(q-2)*8..+8)
    const float* p0 = (q < 2) ? (W1dg + h * C_ + q * 8) : (W1vg + h * V_ + (q - 2) * 8);
    s0[m][0] = reinterpret_cast<const float4*>(p0)[0];
    s0[m][1] = reinterpret_cast<const float4*>(p0)[1];
  }
#pragma unroll
  for (int m = 0; m < 4; ++m) {
    // frag1 k=32+q*8: q<2 -> W1v[h][16+q*8..+8); q>=2 lanes contribute zero
    if (q < 2) {
      const float* p1 = W1vg + (m * 16 + c) * V_ + 16 + q * 8;
      s1[m][0] = reinterpret_cast<const float4*>(p1)[0];
      s1[m][1] = reinterpret_cast<const float4*>(p1)[1];
    }
  }
  float4 w2s[2][2];
  {
    const float* pw2 = W2 + (size_t)g * (O_ * H_) + (c & 3) * H_ + q * 8;
    w2s[0][0] = reinterpret_cast<const float4*>(pw2)[0];
    w2s[0][1] = reinterpret_cast<const float4*>(pw2)[1];
    w2s[1][0] = reinterpret_cast<const float4*>(pw2 + 32)[0];
    w2s[1][1] = reinterpret_cast<const float4*>(pw2 + 32)[1];
  }
  float4 bb[4];
#pragma unroll
  for (int m = 0; m < 4; ++m)
    bb[m] = *reinterpret_cast<const float4*>(b1 + (size_t)g * H_ + m * 16 + q * 4);
  const float4 b2v = *reinterpret_cast<const float4*>(b2 + (size_t)g * O_);

  // items: lane(c,q) owns 8 consecutive floats of batch-row (tile*16+c), group g.
  // frag0 q>=2 -> items[(q-2)*8]; frag1 q<2 -> items[16+q*8]  => ioff=((q+2)&3)*8
  const int ioff = ((q + 2) & 3) * 8;
  const float* itbase = items + (size_t)c * (G_ * V_) + (size_t)g * V_ + ioff;
  v4f itA[2], itB[2];
  itA[0] = __builtin_nontemporal_load(reinterpret_cast<const v4f*>(itbase));
  itA[1] = __builtin_nontemporal_load(reinterpret_cast<const v4f*>(itbase) + 1);

  // ---- stage day -> Dl (one-time), lgkm-only barrier ----
  {
#pragma unroll
    for (int i = 0; i < 2; ++i) {
      const int idx = t + i * 256;
      const int b = idx >> 2, col = (idx & 3) << 2;
      *reinterpret_cast<v4bf*>(&Dl[b * DS_ + col]) = cvt4(dd[i]);
    }
  }
  asm volatile("s_waitcnt lgkmcnt(0)" ::: "memory");
  __builtin_amdgcn_s_barrier();
  asm volatile("" ::: "memory");

  // ---- convert burst -> bf16 fragments (frees f32 staging regs) ----
  v8bf wf0[4], wf1[4], w2f[2];
#pragma unroll
  for (int m = 0; m < 4; ++m) wf0[m] = cvt8(s0[m][0], s0[m][1]);
#pragma unroll
  for (int m = 0; m < 4; ++m) wf1[m] = (q < 2) ? cvt8(s1[m][0], s1[m][1]) : zf;
  w2f[0] = (c < O_) ? cvt8(w2s[0][0], w2s[0][1]) : zf;
  w2f[1] = (c < O_) ? cvt8(w2s[1][0], w2s[1][1]) : zf;

  // ---- 8 N-tiles of 16 batches; rolling nt items prefetch; ZERO barriers ----
#define CHUNK(CH, CUR, NXT, PREF)                                              \
  {                                                                            \
    if (PREF) {                                                                \
      const float* p = itbase + (size_t)(((CH) + 1) * 16) * (G_ * V_);         \
      NXT[0] = __builtin_nontemporal_load(reinterpret_cast<const v4f*>(p));    \
      NXT[1] = __builtin_nontemporal_load(reinterpret_cast<const v4f*>(p) + 1);\
    }                                                                          \
    const v8bf dayv =                                                          \
        *reinterpret_cast<const v8bf*>(&Dl[((CH) * 16 + c) * DS_ + (q & 1) * 8]); \
    const v8bf ic  = cvt8v(CUR[0], CUR[1]);                                    \
    const v8bf blv = (q < 2) ? dayv : ic;                                      \
    const v8bf bhv = (q < 2) ? ic : zf;                                        \
    v4f acc[4];                                                                \
    _Pragma("unroll")                                                          \
    for (int m = 0; m < 4; ++m) acc[m] = zero;                                 \
    _Pragma("unroll")                                                          \
    for (int m = 0; m < 4; ++m) {                                              \
      acc[m] = __builtin_amdgcn_mfma_f32_16x16x32_bf16(wf0[m], blv, acc[m], 0, 0, 0); \
      acc[m] = __builtin_amdgcn_mfma_f32_16x16x32_bf16(wf1[m], bhv, acc[m], 0, 0, 0); \
    }                                                                          \
    _Pragma("unroll")                                                          \
    for (int m = 0; m < 4; ++m) {                                              \
      v4bf hv;                                                                 \
      hv[0] = (__bf16)fmaxf(acc[m][0] + bb[m].x, 0.f);                         \
      hv[1] = (__bf16)fmaxf(acc[m][1] + bb[m].y, 0.f);                         \
      hv[2] = (__bf16)fmaxf(acc[m][2] + bb[m].z, 0.f);                         \
      hv[3] = (__bf16)fmaxf(acc[m][3] + bb[m].w, 0.f);                         \
      *reinterpret_cast<v4bf*>(&Hb[w][c * HS_ + m * 16 + q * 4]) = hv;         \
    }                                                                          \
    v4f y = zero;                                                              \
    _Pragma("unroll")                                                          \
    for (int kt = 0; kt < 2; ++kt) {                                           \
      const v8bf hf =                                                          \
          *reinterpret_cast<const v8bf*>(&Hb[w][c * HS_ + kt * 32 + q * 8]);   \
      y = __builtin_amdgcn_mfma_f32_16x16x32_bf16(w2f[kt], hf, y, 0, 0, 0);    \
    }                                                                          \
    if (q == 0) {                                                              \
      float4 o;                                                                \
      o.x = y[0] + b2v.x; o.y = y[1] + b2v.y;                                  \
      o.z = y[2] + b2v.z; o.w = y[3] + b2v.w;                                  \
      *reinterpret_cast<float4*>(out + (size_t)((CH) * 16 + c) * (G_ * O_) +   \
                                 (size_t)g * O_) = o;                          \
    }                                                                          \
  }

  CHUNK(0, itA, itB, 1)
  CHUNK(1, itB, itA, 1)
  CHUNK(2, itA, itB, 1)
  CHUNK(3, itB, itA, 1)
  CHUNK(4, itA, itB, 1)
  CHUNK(5, itB, itA, 1)
  CHUNK(6, itA, itB, 1)
  CHUNK(7, itB, itA, 0)
#undef CHUNK
}

extern "C" void kernel_launch(void* const* d_in, const int* in_sizes, int n_in,
                              void* d_out, int out_size, void* d_ws, size_t ws_size,
                              hipStream_t stream) {
  const float* day   = (const float*)d_in[0];
  const float* items = (const float*)d_in[1];
  const float* W1d   = (const float*)d_in[2];
  const float* W1v   = (const float*)d_in[3];
  const float* b1    = (const float*)d_in[4];
  const float* W2    = (const float*)d_in[5];
  const float* b2    = (const float*)d_in[6];
  float* out = (float*)d_out;
  splitmlp_kernel<<<G_ / GPB, 256, 0, stream>>>(day, items, W1d, W1v, b1, W2, b2, out);
}